// Round 1
// baseline (40.283 us; speedup 1.0000x reference)
//
#include <hip/hip_runtime.h>
#include <math.h>

// RecurrentNALU single step, fp32.
// B=4096, IN=128, HID=128, CAT=256.
// y = g*a + (1-g)*m where
//   g = sigmoid(x @ G.T), a = x @ clip(Wa,-1,1).T,
//   m = prod_c (x*clip(Wm,0,1) + 1 - clip(Wm,0,1))
//
// Layout: lane = row, wave = 4 output cols, block = 64 rows x 16 cols.
// x staged transposed in LDS (XOR-swizzled), weights via wave-uniform s_loads.

#define BATCH    4096
#define IN_SIZE  128
#define HID      128
#define CAT      256
#define BR       64            // rows per block
#define CPW      4             // cols per wave
#define NWAVES   4
#define CPB      (CPW * NWAVES) // 16 cols per block

__global__ __launch_bounds__(256, 2)
void nalu_step_kernel(const float* __restrict__ x_t,
                      const float* __restrict__ h_tm1,
                      const float* __restrict__ W_add,
                      const float* __restrict__ W_mul,
                      const float* __restrict__ G_add,
                      float* __restrict__ out)
{
    // xT[c][r'] with r' = r ^ f(c); 256*64 floats = 64 KB
    __shared__ float xT[CAT * BR];

    const int tid = threadIdx.x;
    const int colBlocks = HID / CPB;           // 8
    const int rowBlk = blockIdx.x / colBlocks; // 0..63
    const int colBlk = blockIdx.x % colBlocks; // 0..7
    const int rowBase = rowBlk * BR;

    // ---- stage x = concat(x_t, h_tm1), transposed, into LDS ----
    // 64 rows x 256 cols = 4096 float4s; 256 threads -> 16 float4 each.
    // Consecutive tids read consecutive float4s within a row -> coalesced.
    #pragma unroll
    for (int i = 0; i < 16; ++i) {
        const int idx4 = tid + i * 256;   // 0..4095
        const int r = idx4 >> 6;          // row within tile
        const int c = (idx4 & 63) * 4;    // col (multiple of 4)
        const float* src = (c < IN_SIZE)
            ? (x_t  + (size_t)(rowBase + r) * IN_SIZE + c)
            : (h_tm1 + (size_t)(rowBase + r) * HID + (c - IN_SIZE));
        const float4 v = *reinterpret_cast<const float4*>(src);
        // XOR swizzle: logical row r stored at physical slot r ^ f(c)
        {
            const int cc = c + 0, f = (cc ^ (cc >> 2)) & 63;
            xT[cc * BR + (r ^ f)] = v.x;
        }
        {
            const int cc = c + 1, f = (cc ^ (cc >> 2)) & 63;
            xT[cc * BR + (r ^ f)] = v.y;
        }
        {
            const int cc = c + 2, f = (cc ^ (cc >> 2)) & 63;
            xT[cc * BR + (r ^ f)] = v.z;
        }
        {
            const int cc = c + 3, f = (cc ^ (cc >> 2)) & 63;
            xT[cc * BR + (r ^ f)] = v.w;
        }
    }
    __syncthreads();

    const int lane = tid & 63;
    // force wave-uniformity so weight loads scalarize to s_load
    const int wave = __builtin_amdgcn_readfirstlane(tid >> 6);
    const int hBase = colBlk * CPB + wave * CPW;

    const float* __restrict__ Wa = W_add + (size_t)hBase * CAT;
    const float* __restrict__ Wm = W_mul + (size_t)hBase * CAT;
    const float* __restrict__ Ga = G_add + (size_t)hBase * CAT;

    float acc_a[CPW] = {0.f, 0.f, 0.f, 0.f};
    float acc_g[CPW] = {0.f, 0.f, 0.f, 0.f};
    float acc_m[CPW] = {1.f, 1.f, 1.f, 1.f};

    #pragma unroll 4
    for (int c = 0; c < CAT; ++c) {
        const int f = (c ^ (c >> 2)) & 63;       // scalar
        const float xv = xT[c * BR + (lane ^ f)]; // conflict-free broadcast-free read
        const float xm1 = xv - 1.0f;
        #pragma unroll
        for (int j = 0; j < CPW; ++j) {
            float wa = Wa[(size_t)j * CAT + c];
            wa = fminf(fmaxf(wa, -1.0f), 1.0f);
            float wm = Wm[(size_t)j * CAT + c];
            wm = fminf(fmaxf(wm, 0.0f), 1.0f);
            const float gv = Ga[(size_t)j * CAT + c];
            acc_a[j] = fmaf(xv, wa, acc_a[j]);
            acc_g[j] = fmaf(xv, gv, acc_g[j]);
            // x*wm + 1 - wm == fma(wm, x-1, 1)
            acc_m[j] *= fmaf(wm, xm1, 1.0f);
        }
    }

    // ---- epilogue: sigmoid gate + blend, store ----
    const int r = rowBase + lane;
    #pragma unroll
    for (int j = 0; j < CPW; ++j) {
        const float z = acc_g[j];
        const float g = 1.0f / (1.0f + __expf(-z));
        const float y = g * acc_a[j] + (1.0f - g) * acc_m[j];
        out[(size_t)r * HID + hBase + j] = y;
    }
}

extern "C" void kernel_launch(void* const* d_in, const int* in_sizes, int n_in,
                              void* d_out, int out_size, void* d_ws, size_t ws_size,
                              hipStream_t stream)
{
    const float* x_t   = (const float*)d_in[0];
    const float* h_tm1 = (const float*)d_in[1];
    const float* W_add = (const float*)d_in[2];
    const float* W_mul = (const float*)d_in[3];
    const float* G_add = (const float*)d_in[4];
    float* out = (float*)d_out;

    const int grid = (BATCH / BR) * (HID / CPB); // 64 * 8 = 512 blocks
    nalu_step_kernel<<<grid, 256, 0, stream>>>(x_t, h_tm1, W_add, W_mul, G_add, out);
}

// Round 2
// 28.197 us; speedup vs baseline: 1.4286x; 1.4286x over previous
//
#include <hip/hip_runtime.h>
#include <math.h>

// RecurrentNALU single step, fp32. B=4096, IN=128, HID=128, CAT=256.
// Round 2: pre-clamped weights (prep kernel -> d_ws), packed fp32 (v_pk_fma_f32)
// over c-pairs, chunked double-buffered LDS staging (32 KB), CPW=2 for
// 16 waves/CU, XCD-bijective block swizzle.

#define BATCH    4096
#define IN_SIZE  128
#define HID      128
#define CAT      256
#define BR       64              // rows per block
#define CHUNK    64              // c per staged chunk
#define NCHUNK   (CAT / CHUNK)   // 4
#define CPW      2               // cols per wave
#define NWAVES   4
#define CPB      (CPW * NWAVES)  // 8 cols per block
#define COLB     (HID / CPB)     // 16 column blocks
#define GRID     ((BATCH / BR) * COLB) // 1024

typedef float f32x2 __attribute__((ext_vector_type(2)));

static __device__ __forceinline__ f32x2 vfma(f32x2 a, f32x2 b, f32x2 c) {
#if __has_builtin(__builtin_elementwise_fma)
    return __builtin_elementwise_fma(a, b, c);
#else
    f32x2 r; r.x = fmaf(a.x, b.x, c.x); r.y = fmaf(a.y, b.y, c.y); return r;
#endif
}

// ---- prep: clamp weights once into workspace ----
__global__ __launch_bounds__(256)
void preclamp_kernel(const float4* __restrict__ Wa, const float4* __restrict__ Wm,
                     float4* __restrict__ ws)
{
    const int i = blockIdx.x * 256 + threadIdx.x; // 0..16383
    if (i < 8192) {
        float4 v = Wa[i];
        v.x = fminf(fmaxf(v.x, -1.f), 1.f);
        v.y = fminf(fmaxf(v.y, -1.f), 1.f);
        v.z = fminf(fmaxf(v.z, -1.f), 1.f);
        v.w = fminf(fmaxf(v.w, -1.f), 1.f);
        ws[i] = v;
    } else {
        float4 v = Wm[i - 8192];
        v.x = fminf(fmaxf(v.x, 0.f), 1.f);
        v.y = fminf(fmaxf(v.y, 0.f), 1.f);
        v.z = fminf(fmaxf(v.z, 0.f), 1.f);
        v.w = fminf(fmaxf(v.w, 0.f), 1.f);
        ws[i] = v;
    }
}

// ---- main kernel ----
// LDS layout (per chunk buffer): pair q in [0,32), slot p = (r ^ g(q))*2,
// g(q) = (q>>1)&15. float index = q*128 + p + k. Conflict-even for both the
// transpose staging writes (b64) and the broadcast-free compute reads (b64).
template<bool PRECLAMP>
__global__ __launch_bounds__(256, 4)
void nalu_step_kernel(const float* __restrict__ x_t,
                      const float* __restrict__ h_tm1,
                      const float* __restrict__ Wa_,
                      const float* __restrict__ Wm_,
                      const float* __restrict__ Ga_,
                      float* __restrict__ out)
{
    __shared__ float xs[2][CHUNK * BR]; // 2 x 16 KB

    // XCD-bijective swizzle (GRID % 8 == 0): contiguous logical chunk per XCD
    const int bid = blockIdx.x;
    const int cpx = GRID >> 3;
    const int wg  = (bid & 7) * cpx + (bid >> 3);

    const int rowBlk  = wg / COLB;
    const int colBlk  = wg % COLB;
    const int rowBase = rowBlk * BR;

    const int tid  = threadIdx.x;
    const int lane = tid & 63;
    const int wave = __builtin_amdgcn_readfirstlane(tid >> 6);
    const int hBase = colBlk * CPB + wave * CPW;

    // ---- staging helper (macro to keep ch compile-time) ----
#define STAGE(CH, BUF)                                                        \
    do {                                                                      \
        const float* __restrict__ sbase = ((CH) < 2) ? x_t : h_tm1;           \
        const int colOff = ((CH) & 1) * 64;                                   \
        _Pragma("unroll")                                                     \
        for (int it = 0; it < 4; ++it) {                                      \
            const int idx4 = tid + it * 256;                                  \
            const int r = idx4 >> 4;                                          \
            const int u = idx4 & 15;                                          \
            const float4 v = *reinterpret_cast<const float4*>(                \
                sbase + (size_t)(rowBase + r) * 128 + colOff + u * 4);        \
            const int p = ((r ^ u) << 1);                                     \
            float* d0 = &xs[BUF][(2 * u) * 128 + p];                          \
            float* d1 = &xs[BUF][(2 * u + 1) * 128 + p];                      \
            *reinterpret_cast<float2*>(d0) = make_float2(v.x, v.y);           \
            *reinterpret_cast<float2*>(d1) = make_float2(v.z, v.w);           \
        }                                                                     \
    } while (0)

    f32x2 aa[CPW], ag[CPW], am[CPW];
    #pragma unroll
    for (int j = 0; j < CPW; ++j) {
        aa[j] = (f32x2){0.f, 0.f};
        ag[j] = (f32x2){0.f, 0.f};
        am[j] = (f32x2){1.f, 1.f};
    }

    STAGE(0, 0);
    __syncthreads();

    #pragma unroll
    for (int ch = 0; ch < NCHUNK; ++ch) {
        const int cur = ch & 1;
        if (ch == 0) STAGE(1, 1);
        if (ch == 1) STAGE(2, 0);
        if (ch == 2) STAGE(3, 1);

        const float* __restrict__ wa0 = Wa_ + (size_t)hBase * CAT + ch * CHUNK;
        const float* __restrict__ wm0 = Wm_ + (size_t)hBase * CAT + ch * CHUNK;
        const float* __restrict__ ga0 = Ga_ + (size_t)hBase * CAT + ch * CHUNK;

        #pragma unroll 8
        for (int q = 0; q < CHUNK / 2; ++q) {
            const int g = (q >> 1) & 15;
            const f32x2 x2 = *reinterpret_cast<const f32x2*>(
                &xs[cur][q * 128 + ((lane ^ g) << 1)]);
            const f32x2 xm1 = x2 - 1.0f;
            #pragma unroll
            for (int j = 0; j < CPW; ++j) {
                f32x2 wa = *reinterpret_cast<const f32x2*>(wa0 + (size_t)j * CAT + 2 * q);
                f32x2 wm = *reinterpret_cast<const f32x2*>(wm0 + (size_t)j * CAT + 2 * q);
                const f32x2 gv = *reinterpret_cast<const f32x2*>(ga0 + (size_t)j * CAT + 2 * q);
                if (!PRECLAMP) {
#if __has_builtin(__builtin_elementwise_min) && __has_builtin(__builtin_elementwise_max)
                    wa = __builtin_elementwise_min(
                             __builtin_elementwise_max(wa, (f32x2){-1.f, -1.f}),
                             (f32x2){1.f, 1.f});
                    wm = __builtin_elementwise_min(
                             __builtin_elementwise_max(wm, (f32x2){0.f, 0.f}),
                             (f32x2){1.f, 1.f});
#else
                    wa.x = fminf(fmaxf(wa.x, -1.f), 1.f);
                    wa.y = fminf(fmaxf(wa.y, -1.f), 1.f);
                    wm.x = fminf(fmaxf(wm.x, 0.f), 1.f);
                    wm.y = fminf(fmaxf(wm.y, 0.f), 1.f);
#endif
                }
                aa[j] = vfma(x2, wa, aa[j]);
                ag[j] = vfma(x2, gv, ag[j]);
                am[j] = am[j] * vfma(wm, xm1, (f32x2){1.f, 1.f});
            }
        }
        __syncthreads();
    }
#undef STAGE

    // ---- epilogue ----
    const int r = rowBase + lane;
    #pragma unroll
    for (int j = 0; j < CPW; ++j) {
        const float a = aa[j].x + aa[j].y;
        const float z = ag[j].x + ag[j].y;
        const float m = am[j].x * am[j].y;
        const float gg = 1.0f / (1.0f + __expf(-z));
        out[(size_t)r * HID + hBase + j] = gg * a + (1.0f - gg) * m;
    }
}

extern "C" void kernel_launch(void* const* d_in, const int* in_sizes, int n_in,
                              void* d_out, int out_size, void* d_ws, size_t ws_size,
                              hipStream_t stream)
{
    const float* x_t   = (const float*)d_in[0];
    const float* h_tm1 = (const float*)d_in[1];
    const float* W_add = (const float*)d_in[2];
    const float* W_mul = (const float*)d_in[3];
    const float* G_add = (const float*)d_in[4];
    float* out = (float*)d_out;

    const size_t needed = (size_t)2 * HID * CAT * sizeof(float); // 256 KB
    if (ws_size >= needed && d_ws) {
        float* ws = (float*)d_ws;
        preclamp_kernel<<<64, 256, 0, stream>>>(
            (const float4*)W_add, (const float4*)W_mul, (float4*)ws);
        nalu_step_kernel<true><<<GRID, 256, 0, stream>>>(
            x_t, h_tm1, ws, ws + (size_t)HID * CAT, G_add, out);
    } else {
        nalu_step_kernel<false><<<GRID, 256, 0, stream>>>(
            x_t, h_tm1, W_add, W_mul, G_add, out);
    }
}